// Round 1
// baseline (649.712 us; speedup 1.0000x reference)
//
#include <hip/hip_runtime.h>
#include <hip/hip_bf16.h>

using bf16   = __bf16;
using bf16x4 = __attribute__((ext_vector_type(4))) __bf16;
using bf16x8 = __attribute__((ext_vector_type(8))) __bf16;
using f32x4  = __attribute__((ext_vector_type(4))) float;

#define B_TOT 2048
#define NTOK  98
#define CDIM  192
#define NHEAD 6
#define HDIM  32
#define NWIN  512
#define NN    (NTOK*NTOK)            /* 9604 */
#define QKV_ELEMS ((size_t)B_TOT*NHEAD*NTOK*HDIM)  /* 38535168 */
#define SCALE 0.17677669529663687f   /* 32^-0.5 */

#define MFMA(a,b,c) __builtin_amdgcn_mfma_f32_16x16x32_bf16((a),(b),(c),0,0,0)

// ---------------------------------------------------------------------------
// Kernel 0: bias[h][i][j] = rpb_table[rel_pos_index[i*98+j]][h]
// ---------------------------------------------------------------------------
__global__ void build_bias(const float* __restrict__ table,
                           const int* __restrict__ rel,
                           float* __restrict__ bias) {
    int t = blockIdx.x * 256 + threadIdx.x;
    if (t < NN) {
        int idx = rel[t];
        #pragma unroll
        for (int h = 0; h < NHEAD; ++h)
            bias[h * NN + t] = table[idx * NHEAD + h];
    }
}

// ---------------------------------------------------------------------------
// Kernel 1: QKV GEMM. M=200704 K=192 N=576, BM=128, B-chunks of 64 cols.
// A (x f32->bf16) and B (qkv_w f32->bf16) staged in XOR-swizzled LDS.
// Stores q*scale, k as [b][h][n][hd] bf16; v transposed [b][h][hd][n] bf16.
// ---------------------------------------------------------------------------
__global__ __launch_bounds__(256) void qkv_gemm(
    const float* __restrict__ x, const float* __restrict__ w,
    const float* __restrict__ bvec,
    bf16* __restrict__ qdst, bf16* __restrict__ kdst, bf16* __restrict__ vdst)
{
    __shared__ char lds[49152 + 24576];
    char* As = lds;            // 128 rows * 384 B (192 bf16), swizzled
    char* Bs = lds + 49152;    // 64 rows * 384 B, swizzled

    const int tid = threadIdx.x;
    const int m0  = blockIdx.x * 128;

    // stage A: 128x192 f32 -> bf16 (rows = tokens, swizzle chunk^= row&7)
    for (int c = tid; c < 128 * 48; c += 256) {
        int row = c / 48, c4 = c % 48;
        const float4 v = *(const float4*)(x + (size_t)(m0 + row) * CDIM + c4 * 4);
        bf16x4 p; p[0] = (bf16)v.x; p[1] = (bf16)v.y; p[2] = (bf16)v.z; p[3] = (bf16)v.w;
        *(bf16x4*)(As + row * 384 + ((((c4 >> 1) ^ (row & 7)) << 4) | ((c4 & 1) << 3))) = p;
    }

    const int lane = tid & 63, wave = tid >> 6;
    const int wr = wave >> 1, wc = wave & 1;
    const int l15 = lane & 15, l16 = lane >> 4;
    const f32x4 z4 = {0.f, 0.f, 0.f, 0.f};

    for (int nc = 0; nc < 9; ++nc) {
        __syncthreads();   // Bs free from previous iteration (also fences As on iter 0 path below)
        for (int c = tid; c < 64 * 48; c += 256) {
            int row = c / 48, c4 = c % 48;
            const float4 v = *(const float4*)(w + (size_t)(nc * 64 + row) * CDIM + c4 * 4);
            bf16x4 p; p[0] = (bf16)v.x; p[1] = (bf16)v.y; p[2] = (bf16)v.z; p[3] = (bf16)v.w;
            *(bf16x4*)(Bs + row * 384 + ((((c4 >> 1) ^ (row & 7)) << 4) | ((c4 & 1) << 3))) = p;
        }
        __syncthreads();

        f32x4 acc[4][2];
        #pragma unroll
        for (int i = 0; i < 4; ++i)
            #pragma unroll
            for (int j = 0; j < 2; ++j) acc[i][j] = z4;

        #pragma unroll
        for (int ks = 0; ks < 6; ++ks) {
            const int kchunk = ks * 4 + l16;   // 16B chunk index along K
            bf16x8 af[4];
            #pragma unroll
            for (int it = 0; it < 4; ++it) {
                int row = wr * 64 + it * 16 + l15;
                af[it] = *(const bf16x8*)(As + row * 384 + ((kchunk ^ (row & 7)) << 4));
            }
            #pragma unroll
            for (int ct = 0; ct < 2; ++ct) {
                int row = wc * 32 + ct * 16 + l15;
                bf16x8 bfr = *(const bf16x8*)(Bs + row * 384 + ((kchunk ^ (row & 7)) << 4));
                #pragma unroll
                for (int it = 0; it < 4; ++it)
                    acc[it][ct] = MFMA(af[it], bfr, acc[it][ct]);
            }
        }

        // scatter-store into q/k/v layouts
        #pragma unroll
        for (int it = 0; it < 4; ++it) {
            #pragma unroll
            for (int ct = 0; ct < 2; ++ct) {
                #pragma unroll
                for (int r = 0; r < 4; ++r) {
                    int col = nc * 64 + wc * 32 + ct * 16 + l15;
                    int row = m0 + wr * 64 + it * 16 + l16 * 4 + r;
                    float v = acc[it][ct][r] + bvec[col];
                    int which = col / CDIM, cm = col % CDIM;
                    int h = cm >> 5, hd = cm & 31;
                    int b = row / NTOK, n = row % NTOK;
                    if (which == 0)
                        qdst[(((size_t)b * NHEAD + h) * NTOK + n) * HDIM + hd] = (bf16)(v * SCALE);
                    else if (which == 1)
                        kdst[(((size_t)b * NHEAD + h) * NTOK + n) * HDIM + hd] = (bf16)v;
                    else
                        vdst[(((size_t)b * NHEAD + h) * HDIM + hd) * NTOK + n] = (bf16)v;
                }
            }
        }
    }
}

// ---------------------------------------------------------------------------
// Kernel 2: fused attention. One block per (window, head); 7 waves, each owns
// a 16-row S block (N padded 98->112). Q/K fragments straight from global,
// wave-parallel softmax, P in swizzled LDS (padded to 128 cols), PV via MFMA.
// ---------------------------------------------------------------------------
__global__ __launch_bounds__(448) void attn_fused(
    const bf16* __restrict__ q, const bf16* __restrict__ k,
    const bf16* __restrict__ vT,
    const float* __restrict__ mask, const float* __restrict__ bias,
    bf16* __restrict__ ao)
{
    __shared__ char lds[8192 + 28672];
    char* Vt = lds;           // 32 x 128 bf16, 256B rows, swizzled
    char* P  = lds + 8192;    // 112 x 128 bf16, 256B rows, swizzled

    const int bh = blockIdx.x;
    const int b = bh / NHEAD, h = bh % NHEAD;
    const int w = b & (NWIN - 1);
    const int tid = threadIdx.x, lane = tid & 63, it = tid >> 6;
    const int l15 = lane & 15, l16 = lane >> 4;

    // stage V^T into LDS (zero-pad cols 98..127)
    const bf16* vsrc = vT + (size_t)bh * HDIM * NTOK;
    for (int f = tid; f < HDIM * 128; f += 448) {
        int hd = f >> 7, j = f & 127;
        bf16 val = (j < NTOK) ? vsrc[hd * NTOK + j] : (bf16)0.f;
        *(bf16*)(Vt + hd * 256 + (((j >> 3) ^ (hd & 7)) << 4) + ((j & 7) << 1)) = val;
    }

    // Q fragment (row-clamped for pad rows; those S rows are never stored)
    const bf16* qsrc = q + (size_t)bh * NTOK * HDIM;
    const bf16* ksrc = k + (size_t)bh * NTOK * HDIM;
    int qrow = it * 16 + l15; if (qrow > 97) qrow = 97;
    const bf16x8 qf = *(const bf16x8*)(qsrc + qrow * HDIM + l16 * 8);

    const f32x4 z4 = {0.f, 0.f, 0.f, 0.f};
    f32x4 acc[7];
    #pragma unroll
    for (int jt = 0; jt < 7; ++jt) {
        int kr = jt * 16 + l15; if (kr > 97) kr = 97;
        bf16x8 kf = *(const bf16x8*)(ksrc + kr * HDIM + l16 * 8);
        acc[jt] = MFMA(qf, kf, z4);
    }

    // bias + mask + wave-parallel softmax (rows live across 16-lane groups)
    const float* mrow = mask + (size_t)w * NN;
    const float* brow = bias + (size_t)h * NN;
    float p[7][4];
    #pragma unroll
    for (int r = 0; r < 4; ++r) {
        int i = it * 16 + l16 * 4 + r; if (i > 97) i = 97;
        #pragma unroll
        for (int jt = 0; jt < 7; ++jt) {
            int j = jt * 16 + l15;
            p[jt][r] = (j < NTOK) ? (acc[jt][r] + mrow[i * NTOK + j] + brow[i * NTOK + j])
                                  : -__builtin_inff();
        }
        float m = p[0][r];
        #pragma unroll
        for (int jt = 1; jt < 7; ++jt) m = fmaxf(m, p[jt][r]);
        m = fmaxf(m, __shfl_xor(m, 1, 16));
        m = fmaxf(m, __shfl_xor(m, 2, 16));
        m = fmaxf(m, __shfl_xor(m, 4, 16));
        m = fmaxf(m, __shfl_xor(m, 8, 16));
        float s = 0.f;
        #pragma unroll
        for (int jt = 0; jt < 7; ++jt) { p[jt][r] = __expf(p[jt][r] - m); s += p[jt][r]; }
        s += __shfl_xor(s, 1, 16);
        s += __shfl_xor(s, 2, 16);
        s += __shfl_xor(s, 4, 16);
        s += __shfl_xor(s, 8, 16);
        float inv = 1.f / s;
        #pragma unroll
        for (int jt = 0; jt < 7; ++jt) p[jt][r] *= inv;
    }

    // write P (bf16, swizzled) + zero pad cols 112..127
    #pragma unroll
    for (int jt = 0; jt < 7; ++jt) {
        #pragma unroll
        for (int r = 0; r < 4; ++r) {
            int row = it * 16 + l16 * 4 + r;
            int j = jt * 16 + l15;
            *(bf16*)(P + row * 256 + (((j >> 3) ^ (row & 7)) << 4) + ((j & 7) << 1)) = (bf16)p[jt][r];
        }
    }
    {
        int zr = it * 16 + l15;
        int zc = 112 + l16 * 4;
        *(unsigned long long*)(P + zr * 256 + (((zc >> 3) ^ (zr & 7)) << 4) + ((zc & 7) << 1)) = 0ull;
    }
    __syncthreads();   // Vt staged by all threads; also drains own-wave P writes

    // PV: O(16x32) per wave, K-loop over 128 padded j
    f32x4 o0 = z4, o1 = z4;
    const int prow = it * 16 + l15;
    #pragma unroll
    for (int ks = 0; ks < 4; ++ks) {
        int kchunk = ks * 4 + l16;
        bf16x8 pf = *(const bf16x8*)(P + prow * 256 + ((kchunk ^ (prow & 7)) << 4));
        bf16x8 v0 = *(const bf16x8*)(Vt + l15 * 256 + ((kchunk ^ (l15 & 7)) << 4));
        bf16x8 v1 = *(const bf16x8*)(Vt + (16 + l15) * 256 + ((kchunk ^ (l15 & 7)) << 4));
        o0 = MFMA(pf, v0, o0);
        o1 = MFMA(pf, v1, o1);
    }

    bf16* dst = ao + (size_t)b * NTOK * CDIM + h * HDIM;
    #pragma unroll
    for (int r = 0; r < 4; ++r) {
        int row = it * 16 + l16 * 4 + r;
        if (row < NTOK) {
            dst[(size_t)row * CDIM + l15]      = (bf16)o0[r];
            dst[(size_t)row * CDIM + 16 + l15] = (bf16)o1[r];
        }
    }
}

// ---------------------------------------------------------------------------
// Kernel 3: proj GEMM. M=200704 K=192 N=192, BM=128, 3 B-chunks of 64 cols.
// ---------------------------------------------------------------------------
__global__ __launch_bounds__(256) void proj_gemm(
    const bf16* __restrict__ ao, const float* __restrict__ w,
    const float* __restrict__ bvec, float* __restrict__ out)
{
    __shared__ char lds[49152 + 24576];
    char* As = lds;
    char* Bs = lds + 49152;
    const int tid = threadIdx.x;
    const int m0  = blockIdx.x * 128;

    for (int c = tid; c < 128 * 24; c += 256) {
        int row = c / 24, c8 = c % 24;
        bf16x8 v = *(const bf16x8*)(ao + (size_t)(m0 + row) * CDIM + c8 * 8);
        *(bf16x8*)(As + row * 384 + ((c8 ^ (row & 7)) << 4)) = v;
    }

    const int lane = tid & 63, wave = tid >> 6;
    const int wr = wave >> 1, wc = wave & 1;
    const int l15 = lane & 15, l16 = lane >> 4;
    const f32x4 z4 = {0.f, 0.f, 0.f, 0.f};

    for (int nc = 0; nc < 3; ++nc) {
        __syncthreads();
        for (int c = tid; c < 64 * 48; c += 256) {
            int row = c / 48, c4 = c % 48;
            const float4 v = *(const float4*)(w + (size_t)(nc * 64 + row) * CDIM + c4 * 4);
            bf16x4 p; p[0] = (bf16)v.x; p[1] = (bf16)v.y; p[2] = (bf16)v.z; p[3] = (bf16)v.w;
            *(bf16x4*)(Bs + row * 384 + ((((c4 >> 1) ^ (row & 7)) << 4) | ((c4 & 1) << 3))) = p;
        }
        __syncthreads();

        f32x4 acc[4][2];
        #pragma unroll
        for (int i = 0; i < 4; ++i)
            #pragma unroll
            for (int j = 0; j < 2; ++j) acc[i][j] = z4;

        #pragma unroll
        for (int ks = 0; ks < 6; ++ks) {
            const int kchunk = ks * 4 + l16;
            bf16x8 af[4];
            #pragma unroll
            for (int it = 0; it < 4; ++it) {
                int row = wr * 64 + it * 16 + l15;
                af[it] = *(const bf16x8*)(As + row * 384 + ((kchunk ^ (row & 7)) << 4));
            }
            #pragma unroll
            for (int ct = 0; ct < 2; ++ct) {
                int row = wc * 32 + ct * 16 + l15;
                bf16x8 bfr = *(const bf16x8*)(Bs + row * 384 + ((kchunk ^ (row & 7)) << 4));
                #pragma unroll
                for (int it = 0; it < 4; ++it)
                    acc[it][ct] = MFMA(af[it], bfr, acc[it][ct]);
            }
        }

        #pragma unroll
        for (int it = 0; it < 4; ++it) {
            #pragma unroll
            for (int ct = 0; ct < 2; ++ct) {
                #pragma unroll
                for (int r = 0; r < 4; ++r) {
                    int col = nc * 64 + wc * 32 + ct * 16 + l15;
                    int row = m0 + wr * 64 + it * 16 + l16 * 4 + r;
                    out[(size_t)row * CDIM + col] = acc[it][ct][r] + bvec[col];
                }
            }
        }
    }
}

// ---------------------------------------------------------------------------
extern "C" void kernel_launch(void* const* d_in, const int* in_sizes, int n_in,
                              void* d_out, int out_size, void* d_ws, size_t ws_size,
                              hipStream_t stream)
{
    (void)in_sizes; (void)n_in; (void)out_size; (void)ws_size;
    const float* x      = (const float*)d_in[0];
    const float* mask   = (const float*)d_in[1];
    const float* qkv_w  = (const float*)d_in[2];
    const float* qkv_b  = (const float*)d_in[3];
    const float* proj_w = (const float*)d_in[4];
    const float* proj_b = (const float*)d_in[5];
    const float* rpb    = (const float*)d_in[6];
    const int*   rel    = (const int*)d_in[7];
    float* out = (float*)d_out;

    char* ws = (char*)d_ws;
    bf16* qb = (bf16*)ws;
    bf16* kb = qb + QKV_ELEMS;
    bf16* vb = kb + QKV_ELEMS;
    size_t off = 3 * QKV_ELEMS * sizeof(bf16);          // 231211008
    float* bias = (float*)(ws + off);
    off += ((size_t)NHEAD * NN * 4 + 255) / 256 * 256;  // bias bytes, aligned
    bf16* ao = (bf16*)(ws + 3 * QKV_ELEMS * sizeof(bf16) + ((size_t)NHEAD * NN * 4 + 255) / 256 * 256);

    build_bias<<<(NN + 255) / 256, 256, 0, stream>>>(rpb, rel, bias);
    qkv_gemm<<<200704 / 128, 256, 0, stream>>>(x, qkv_w, qkv_b, qb, kb, vb);
    attn_fused<<<B_TOT * NHEAD, 448, 0, stream>>>(qb, kb, vb, mask, bias, ao);
    proj_gemm<<<200704 / 128, 256, 0, stream>>>(ao, proj_w, proj_b, out);
}